// Round 5
// baseline (108.794 us; speedup 1.0000x reference)
//
#include <hip/hip_runtime.h>

// Overlapped-chunk HMM forward filter, all-VALU inner loop.
// CHUNK_L=16, WARMUP_W=32 -> 31250 chunks, 7813 waves, ~7.6 waves/SIMD of
// independent 48-step chains (latency-bound regime needs the overlap).
// Dot uses 4-accumulator DPP row_newbcast tree (short critical path, ~24 cyc);
// normalizer via DPP row_ror reduce. Warm-up runs the unnormalized linear
// recurrence, renorming every 8 steps (fp32 range is ample). y software-
// pipelined TWO 4-step blocks ahead (~1000+ cyc) to cover HBM-cold loads
// (the harness's 268MB re-poison flushes L2/L3 between replays).
#define CHUNK_L 16
#define WARMUP_W 32

template<int K> __device__ __forceinline__ float bcast16(float v) {
    // broadcast lane (row_start + K) across the 16-lane row (row_newbcast)
    return __int_as_float(__builtin_amdgcn_update_dpp(
        0, __float_as_int(v), 0x150 | K, 0xF, 0xF, true));
}
template<int N> __device__ __forceinline__ float rowror16(float v) {
    return __int_as_float(__builtin_amdgcn_update_dpp(
        0, __float_as_int(v), 0x120 | N, 0xF, 0xF, true));
}

// (alpha @ P)_j : 4 parallel fma chains of depth 4 + 2-level combine
__device__ __forceinline__ float dot16(float a, const float* pc) {
    float u0 = bcast16<0>(a)  * pc[0];
    float u1 = bcast16<1>(a)  * pc[1];
    float u2 = bcast16<2>(a)  * pc[2];
    float u3 = bcast16<3>(a)  * pc[3];
    u0 = fmaf(bcast16<4>(a),  pc[4],  u0);
    u1 = fmaf(bcast16<5>(a),  pc[5],  u1);
    u2 = fmaf(bcast16<6>(a),  pc[6],  u2);
    u3 = fmaf(bcast16<7>(a),  pc[7],  u3);
    u0 = fmaf(bcast16<8>(a),  pc[8],  u0);
    u1 = fmaf(bcast16<9>(a),  pc[9],  u1);
    u2 = fmaf(bcast16<10>(a), pc[10], u2);
    u3 = fmaf(bcast16<11>(a), pc[11], u3);
    u0 = fmaf(bcast16<12>(a), pc[12], u0);
    u1 = fmaf(bcast16<13>(a), pc[13], u1);
    u2 = fmaf(bcast16<14>(a), pc[14], u2);
    u3 = fmaf(bcast16<15>(a), pc[15], u3);
    return (u0 + u1) + (u2 + u3);
}

__device__ __forceinline__ float rowsum16(float p) {
    p += rowror16<1>(p);
    p += rowror16<2>(p);
    p += rowror16<4>(p);
    p += rowror16<8>(p);
    return p;
}

__global__ __launch_bounds__(256, 8) void hmm_filter_kernel(
    const float* __restrict__ y,
    const float* __restrict__ logits,
    const float* __restrict__ mu,
    const float* __restrict__ log_sigma,
    float* __restrict__ out,
    int T, int nchunks)
{
    __shared__ float Plds[256];
    __shared__ float Ba[256];
    __shared__ float Bb[256];

    const int tid = (int)threadIdx.x;
    const int j   = tid & 15;     // state / column index
    const int g   = tid >> 4;     // row (preamble) / group id (main)

    // ---- P = softmax(logits, axis=-1) ----
    float l = logits[tid];
    float m = l;
    #pragma unroll
    for (int s = 1; s < 16; s <<= 1) m = fmaxf(m, __shfl_xor(m, s, 16));
    float e = __expf(l - m);
    float rs = e;
    #pragma unroll
    for (int s = 1; s < 16; s <<= 1) rs += __shfl_xor(rs, s, 16);
    float Pv = e / rs;
    Plds[tid] = Pv;
    Ba[tid]   = Pv;
    __syncthreads();

    // ---- stationary pi: P^(2^10) via renormalized squaring (cold) ----
    float* cur = Ba;
    float* nxt = Bb;
    for (int itq = 0; itq < 10; ++itq) {
        float acc = 0.f;
        #pragma unroll
        for (int k = 0; k < 16; ++k)
            acc += cur[g * 16 + k] * cur[k * 16 + j];
        float rsum = acc;
        #pragma unroll
        for (int s = 1; s < 16; s <<= 1) rsum += __shfl_xor(rsum, s, 16);
        nxt[tid] = acc / rsum;
        __syncthreads();
        float* tmp = cur; cur = nxt; nxt = tmp;
    }
    // no barriers below this point (early return is safe)

    const float api = cur[j];                 // pi_j (normalized by construction)

    float pc[16];
    #pragma unroll
    for (int k = 0; k < 16; ++k) pc[k] = Plds[k * 16 + j];

    const float muj = mu[j];
    const float isj = __expf(-log_sigma[j]);              // 1/sigma_j
    const float nmj = -muj * isj;                         // z = fma(y, isj, nmj)
    const float lcf = __log2f(0.3989422804014327f * isj); // log2(coef)
    const float K2  = -0.7213475204444817f;               // -0.5*log2(e)
    // g_j(y) = exp2( fma(z*z, K2, lcf) )

    const int chunk = (int)blockIdx.x * 16 + g;
    if (chunk >= nchunks) return;

    const int wfrom = chunk * CHUNK_L;
    int t0 = wfrom - WARMUP_W; if (t0 < 0) t0 = 0;  // clamped: EXACT from t=0
    const int nwb = (wfrom - t0) >> 2;              // warm 4-blocks: 0, 4, or 8
    const int Tm4 = T - 4;
    const int TN  = T << 4;

    float a = api;

    // unnormalized warm-up step: a <- g(t) * (a @ P)   (scale-invariant chain)
    auto wstep = [&](float av, float yt) -> float {
        float up = dot16(av, pc);
        float z  = fmaf(yt, isj, nmj);
        float gj = __builtin_amdgcn_exp2f(fmaf(z * z, K2, lcf));
        return up * gj;
    };
    // normalized step with stores (ut, u_norm); returns posterior, outputs s
    auto mstep = [&](float av, float yt, int off, float& sOut) -> float {
        float up = dot16(av, pc);
        float z  = fmaf(yt, isj, nmj);
        float gj = __builtin_amdgcn_exp2f(fmaf(z * z, K2, lcf));
        float p  = up * gj;
        float s  = rowsum16(p);
        float an = p * __builtin_amdgcn_rcpf(s);
        out[off]      = up;
        out[TN + off] = an;
        sOut = s;
        return an;
    };

    // ---- software pipeline: y two 4-blocks ahead ----
    int t = t0;
    float4 c4 = *(const float4*)(y + t);
    int p1 = t + 4; if (p1 > Tm4) p1 = Tm4;
    float4 n1 = *(const float4*)(y + p1);

    // ---- warm-up: nwb blocks of 4 (renorm every other block) ----
    for (int b = 0; b < nwb; ++b) {
        int p2 = t + 8; if (p2 > Tm4) p2 = Tm4;
        const float4 n2 = *(const float4*)(y + p2);
        a = wstep(a, c4.x);
        a = wstep(a, c4.y);
        a = wstep(a, c4.z);
        a = wstep(a, c4.w);
        if (b & 1) a *= __builtin_amdgcn_rcpf(rowsum16(a));
        c4 = n1; n1 = n2; t += 4;
    }
    // exact normalization before emitting (ut/ft are scale-sensitive)
    a *= __builtin_amdgcn_rcpf(rowsum16(a));

    // ---- main chunk: 4 blocks of 4 emit-steps ----
    int oU = (wfrom << 4) + j;    // Ut index; Un at TN+oU; Ft at 2*TN + t
    #pragma unroll 1
    for (int b = 0; b < (CHUNK_L / 4); ++b) {
        int p2 = t + 8; if (p2 > Tm4) p2 = Tm4;
        const float4 n2 = *(const float4*)(y + p2);
        float s0, s1, s2, s3;
        a = mstep(a, c4.x, oU +  0, s0);
        a = mstep(a, c4.y, oU + 16, s1);
        a = mstep(a, c4.z, oU + 32, s2);
        a = mstep(a, c4.w, oU + 48, s3);
        if (j == 0)
            *(float4*)(out + 2 * TN + t) = make_float4(s0, s1, s2, s3);
        c4 = n1; n1 = n2; t += 4; oU += 64;
    }
}

extern "C" void kernel_launch(void* const* d_in, const int* in_sizes, int n_in,
                              void* d_out, int out_size, void* d_ws, size_t ws_size,
                              hipStream_t stream) {
    const float* y      = (const float*)d_in[0];
    const float* logits = (const float*)d_in[1];
    const float* mu     = (const float*)d_in[2];
    const float* ls     = (const float*)d_in[3];
    float* out = (float*)d_out;
    const int T = in_sizes[0];                 // 500000 = 16 * 31250 (exact chunks)

    const int nchunks = (T + CHUNK_L - 1) / CHUNK_L;
    const int blocks  = (nchunks + 15) / 16;
    hmm_filter_kernel<<<blocks, 256, 0, stream>>>(y, logits, mu, ls, out,
                                                  T, nchunks);
}

// Round 6
// 95.438 us; speedup vs baseline: 1.1399x; 1.1399x over previous
//
#include <hip/hip_runtime.h>

// Overlapped-chunk HMM forward filter, all-VALU inner loop.
// CHUNK_L=32, WARMUP_W=16 -> 15625 chunks, ~3.8 waves/SIMD (R3==R5 showed this
// saturates), total work 1.5x T (was 3x in R5).
// KEY RESTRUCTURE: carry the UNNORMALIZED filtrate p_t = f_t * utt_t between
// steps; serial chain is dot16 -> *g -> dot16 (~25cyc). The rowsum/rcp/output
// normalization hangs off the chain in parallel slack:
//   q = p_prev @ P          (= s_prev * ut)
//   pg = q * g              (= s_prev * f * utt = carried next)
//   s = rowsum(pg)          (= s_prev * f)
//   ut = q*rcp(s_prev), ft = s*rcp(s_prev), utt = pg*rcp(s)
// Renormalize once/4-step block by carrying utt3 (computed anyway for store).
// Dot uses v_pk_fma_f32 (float2 ext-vector, fp-contract fuses) off 16 DPP
// row_newbcast broadcasts. y software-pipelined two 4-blocks ahead.
#define CHUNK_L 32
#define WARMUP_W 16

typedef float v2f __attribute__((ext_vector_type(2)));

template<int K> __device__ __forceinline__ float bcast16(float v) {
    // broadcast lane (row_start + K) across the 16-lane row (row_newbcast)
    return __int_as_float(__builtin_amdgcn_update_dpp(
        0, __float_as_int(v), 0x150 | K, 0xF, 0xF, true));
}
template<int N> __device__ __forceinline__ float rowror16(float v) {
    return __int_as_float(__builtin_amdgcn_update_dpp(
        0, __float_as_int(v), 0x120 | N, 0xF, 0xF, true));
}

__device__ __forceinline__ float rowsum16(float p) {
    p += rowror16<1>(p);
    p += rowror16<2>(p);
    p += rowror16<4>(p);
    p += rowror16<8>(p);
    return p;
}

// (a @ P)_j : 16 DPP broadcasts + 8 v_pk_fma_f32 (2 indep accumulator pairs)
__device__ __forceinline__ float dot16(float a, const v2f* pc2) {
    v2f b0, b1, u01, u23;
    b0.x = bcast16<0>(a);  b0.y = bcast16<1>(a);
    b1.x = bcast16<2>(a);  b1.y = bcast16<3>(a);
    u01 = b0 * pc2[0];
    u23 = b1 * pc2[1];
    b0.x = bcast16<4>(a);  b0.y = bcast16<5>(a);
    b1.x = bcast16<6>(a);  b1.y = bcast16<7>(a);
    u01 = b0 * pc2[2] + u01;
    u23 = b1 * pc2[3] + u23;
    b0.x = bcast16<8>(a);  b0.y = bcast16<9>(a);
    b1.x = bcast16<10>(a); b1.y = bcast16<11>(a);
    u01 = b0 * pc2[4] + u01;
    u23 = b1 * pc2[5] + u23;
    b0.x = bcast16<12>(a); b0.y = bcast16<13>(a);
    b1.x = bcast16<14>(a); b1.y = bcast16<15>(a);
    u01 = b0 * pc2[6] + u01;
    u23 = b1 * pc2[7] + u23;
    v2f u = u01 + u23;
    return u.x + u.y;
}

__global__ __launch_bounds__(256, 4) void hmm_filter_kernel(
    const float* __restrict__ y,
    const float* __restrict__ logits,
    const float* __restrict__ mu,
    const float* __restrict__ log_sigma,
    float* __restrict__ out,
    int T, int nchunks)
{
    __shared__ float Plds[256];
    __shared__ float Ba[256];
    __shared__ float Bb[256];

    const int tid = (int)threadIdx.x;
    const int j   = tid & 15;     // state / column index
    const int g   = tid >> 4;     // row (preamble) / group id (main)

    // ---- P = softmax(logits, axis=-1) ----
    float l = logits[tid];
    float m = l;
    #pragma unroll
    for (int s = 1; s < 16; s <<= 1) m = fmaxf(m, __shfl_xor(m, s, 16));
    float e = __expf(l - m);
    float rs = e;
    #pragma unroll
    for (int s = 1; s < 16; s <<= 1) rs += __shfl_xor(rs, s, 16);
    float Pv = e / rs;
    Plds[tid] = Pv;
    Ba[tid]   = Pv;
    __syncthreads();

    // ---- stationary pi: P^(2^10) via renormalized squaring (cold) ----
    float* cur = Ba;
    float* nxt = Bb;
    for (int itq = 0; itq < 10; ++itq) {
        float acc = 0.f;
        #pragma unroll
        for (int k = 0; k < 16; ++k)
            acc += cur[g * 16 + k] * cur[k * 16 + j];
        float rsum = acc;
        #pragma unroll
        for (int s = 1; s < 16; s <<= 1) rsum += __shfl_xor(rsum, s, 16);
        nxt[tid] = acc / rsum;
        __syncthreads();
        float* tmp = cur; cur = nxt; nxt = tmp;
    }
    // no barriers below this point (early return is safe)

    const float api = cur[j];                 // pi_j

    // P column j as 8 float2 pairs (k ascending)
    v2f pc2[8];
    #pragma unroll
    for (int k = 0; k < 8; ++k) {
        pc2[k].x = Plds[(2 * k)     * 16 + j];
        pc2[k].y = Plds[(2 * k + 1) * 16 + j];
    }

    const float muj = mu[j];
    const float isj = __expf(-log_sigma[j]);              // 1/sigma_j
    const float nmj = -muj * isj;                         // z = fma(y, isj, nmj)
    const float lcf = __log2f(0.3989422804014327f * isj); // log2(coef)
    const float K2  = -0.7213475204444817f;               // -0.5*log2(e)
    // g_j(y) = exp2( fma(z*z, K2, lcf) )

    const int chunk = (int)blockIdx.x * 16 + g;
    if (chunk >= nchunks) return;

    const int wfrom = chunk * CHUNK_L;
    int t0 = wfrom - WARMUP_W; if (t0 < 0) t0 = 0;  // chunk 0: EXACT from t=0
    const int nwb = (wfrom - t0) >> 2;              // warm 4-blocks: 0 or 4
    const int Tm4 = T - 4;
    const int TN  = T << 4;

    // emission density (single v_exp_f32)
    auto emis = [&](float yt) -> float {
        float z = fmaf(yt, isj, nmj);
        return __builtin_amdgcn_exp2f(fmaf(z * z, K2, lcf));
    };

    float p = api;   // carried (possibly unnormalized) filtrate
    int t = t0;

    // ---- software pipeline: y two 4-blocks ahead ----
    float4 c4 = *(const float4*)(y + t);
    int pf = t + 4; if (pf > Tm4) pf = Tm4;
    float4 n1 = *(const float4*)(y + pf);

    // ---- warm-up: unnormalized chain, one mid renorm (underflow guard) ----
    for (int b = 0; b < nwb; ++b) {
        int p2 = t + 8; if (p2 > Tm4) p2 = Tm4;
        const float4 n2 = *(const float4*)(y + p2);
        p = dot16(p, pc2) * emis(c4.x);
        p = dot16(p, pc2) * emis(c4.y);
        p = dot16(p, pc2) * emis(c4.z);
        p = dot16(p, pc2) * emis(c4.w);
        if (b == 1) p *= __builtin_amdgcn_rcpf(rowsum16(p));
        c4 = n1; n1 = n2; t += 4;
    }
    // exact normalization entering the main chunk (block assumes c=1)
    p *= __builtin_amdgcn_rcpf(rowsum16(p));

    // ---- main chunk: 8 blocks of 4 steps, carried-product normalization ----
    float* __restrict__ pU = out + (wfrom << 4) + j;   // ut
    float* __restrict__ pN = pU + TN;                  // u_norm
    float* __restrict__ pF = out + 2 * TN + wfrom;     // ft (lane j==0)

    #pragma unroll 1
    for (int b = 0; b < (CHUNK_L / 4); ++b) {
        int p2 = t + 8; if (p2 > Tm4) p2 = Tm4;
        const float4 n2 = *(const float4*)(y + p2);

        // step 0 (entering scale c = 1)
        const float q0  = dot16(p, pc2);        // = ut0
        const float pg0 = q0 * emis(c4.x);
        const float s0  = rowsum16(pg0);        // = ft0
        const float r0  = __builtin_amdgcn_rcpf(s0);
        // step 1 (scale s0)
        const float q1  = dot16(pg0, pc2);      // = s0*ut1
        const float pg1 = q1 * emis(c4.y);
        const float s1  = rowsum16(pg1);        // = s0*ft1
        const float r1  = __builtin_amdgcn_rcpf(s1);
        // step 2 (scale s1)
        const float q2  = dot16(pg1, pc2);
        const float pg2 = q2 * emis(c4.z);
        const float s2  = rowsum16(pg2);
        const float r2  = __builtin_amdgcn_rcpf(s2);
        // step 3 (scale s2)
        const float q3  = dot16(pg2, pc2);
        const float pg3 = q3 * emis(c4.w);
        const float s3  = rowsum16(pg3);
        const float r3  = __builtin_amdgcn_rcpf(s3);

        // outputs (off the serial chain)
        pU[0]  = q0;
        pU[16] = q1 * r0;
        pU[32] = q2 * r1;
        pU[48] = q3 * r2;
        pN[0]  = pg0 * r0;
        pN[16] = pg1 * r1;
        pN[32] = pg2 * r2;
        const float utt3 = pg3 * r3;
        pN[48] = utt3;
        if (j == 0)
            *(float4*)pF = make_float4(s0, s1 * r0, s2 * r1, s3 * r2);

        p = utt3;                                // renormalized carry
        pU += 64; pN += 64; pF += 4;
        c4 = n1; n1 = n2; t += 4;
    }
}

extern "C" void kernel_launch(void* const* d_in, const int* in_sizes, int n_in,
                              void* d_out, int out_size, void* d_ws, size_t ws_size,
                              hipStream_t stream) {
    const float* y      = (const float*)d_in[0];
    const float* logits = (const float*)d_in[1];
    const float* mu     = (const float*)d_in[2];
    const float* ls     = (const float*)d_in[3];
    float* out = (float*)d_out;
    const int T = in_sizes[0];                 // 500000 = 32 * 15625 (exact)

    const int nchunks = (T + CHUNK_L - 1) / CHUNK_L;
    const int blocks  = (nchunks + 15) / 16;
    hmm_filter_kernel<<<blocks, 256, 0, stream>>>(y, logits, mu, ls, out,
                                                  T, nchunks);
}